// Round 1
// baseline (161.874 us; speedup 1.0000x reference)
//
#include <hip/hip_runtime.h>
#include <math.h>

#define T34 34

// ws float offsets
#define PW_OFF  0       // P'[34][34]  (row stride 34)
#define TOK_OFF 1156    // tok_table[10][2]
#define POS_OFF 1184    // pos[34][4]  (raw pre-norm positional vectors, padded)
#define HA_OFF  1320    // hA[2]

// ---------------------------------------------------------------------------
// Kernel A: build the batch-independent tables.
// Attention scores depend only on t because |tok[d]|^2 == A^2 for every digit,
// so rms(x) is digit-independent -> q,k are functions of t only.
// ---------------------------------------------------------------------------
__global__ __launch_bounds__(64) void prep_kernel(
    const float* __restrict__ pA, const float* __restrict__ pStart,
    const float* __restrict__ pStride, const float* __restrict__ zhi,
    const float* __restrict__ spe, const float* __restrict__ qw,
    const float* __restrict__ qph, const float* __restrict__ opA,
    const float* __restrict__ wn, const float* __restrict__ H,
    float* __restrict__ ws)
{
    __shared__ float sK[T34][4];   // k[t] = K0[t]/rho[t]
    __shared__ float sInv[T34];    // 1/rho[t]
    const int t = blockIdx.x;      // 0..33 : this block owns attention row t
    const int s = threadIdx.x;     // 0..63
    const float A = pA[0];

    if (s < T34) {
        // pos table per _SRC/_IDX/_OFFS: t<10 digit(t); 10 zeros; 11..20 digit(t-11);
        // 21 special_pos_equals; 22..31 digit(t-22); 32 z_hi_pos; 33 zeros.
        float p0 = 0.f, p1 = 0.f, p2 = 0.f;
        if (s == 21)      { p0 = spe[0]; p1 = spe[1]; p2 = spe[2]; }
        else if (s == 32) { p0 = zhi[0]; p1 = zhi[1]; p2 = zhi[2]; }
        else if (s != 10 && s != 33) {
            int i = (s < 10) ? s : (s < 21 ? s - 11 : s - 22);
            float a = 0.62831853071795864769f * (float)i;   // 2*pi*i/10
            p0 = 3.5f * cosf(a); p1 = 3.5f * sinf(a); p2 = 0.15f * (float)i;
        }
        float inv = rsqrtf((A*A + p0*p0 + p1*p1 + p2*p2) * 0.2f + 1e-5f);
        float c0 = p0 * wn[2], c1 = p1 * wn[3], c2 = p2 * wn[4];
        #pragma unroll
        for (int j = 0; j < 4; ++j)
            sK[s][j] = (c0*qw[j*3+0] + c1*qw[j*3+1] + c2*qw[j*3+2]) * inv;
        sInv[s] = inv;
        if (s == t) {
            ws[POS_OFF + 4*t + 0] = p0;
            ws[POS_OFF + 4*t + 1] = p1;
            ws[POS_OFF + 4*t + 2] = p2;
            ws[POS_OFF + 4*t + 3] = 0.f;
        }
    }
    __syncthreads();

    // rotate q for row t; k stays unrotated (k = q pre-rotation in the ref)
    float cc = cosf(qph[0]), sn = sinf(qph[0]);
    float k0 = sK[t][0], k1 = sK[t][1], k2 = sK[t][2], k3 = sK[t][3];
    float q0 = k0*cc - k1*sn, q1 = k0*sn + k1*cc;
    float q2 = k2*cc - k3*sn, q3 = k2*sn + k3*cc;

    // causal softmax row t (scores bounded ~|q||k|/2 < ~25 -> max-free exp safe)
    float e = 0.f;
    if (s <= t && s < T34) {
        float d = 0.5f*(q0*sK[s][0] + q1*sK[s][1] + q2*sK[s][2] + q3*sK[s][3]);
        e = expf(d);
    }
    float Z = e;
    #pragma unroll
    for (int off = 1; off < 64; off <<= 1) Z += __shfl_xor(Z, off);
    if (s < T34) ws[PW_OFF + t*T34 + s] = (s <= t) ? (e / Z) * sInv[s] : 0.f;

    if (t == 0) {
        if (s < 10) {
            float ang = pStart[0] + (float)s * pStride[0];
            ws[TOK_OFF + 2*s + 0] = A * cosf(ang);
            ws[TOK_OFF + 2*s + 1] = A * sinf(ang);
        } else if (s == 10) {
            // hA[j] = w[j] * sum_h H[j][h]*out_proj_A[h]  (collapses out@A@B to g*B)
            float a0 = 0.f, a1 = 0.f;
            #pragma unroll
            for (int h = 0; h < 5; ++h) { a0 += H[h]*opA[h]; a1 += H[5+h]*opA[h]; }
            ws[HA_OFF + 0] = a0 * wn[0];
            ws[HA_OFF + 1] = a1 * wn[1];
        }
    }
}

// ---------------------------------------------------------------------------
// Kernel B: main. grid (1024 b-chunks, 5 t-chunks), block (64 b, 7 t).
// Each wave = 64 batches at ONE t (zero divergence; P' row via scalar loads).
// Stages 64 idx rows coalesced -> bf16x2-packed token embeddings in LDS.
// ---------------------------------------------------------------------------
__global__ __launch_bounds__(448) void micro_kernel(
    const int*  __restrict__ idx,
    const float* __restrict__ pA, const float* __restrict__ pStart,
    const float* __restrict__ pStride,
    const float* __restrict__ opB, const float* __restrict__ wn,
    const float* __restrict__ fc1, const float* __restrict__ H,
    const float* __restrict__ ws,
    float* __restrict__ out)
{
    __shared__ unsigned su[64*35];       // [b'][s] stride 35 -> bank stride 3 (2-way, free)
    const int lane = threadIdx.x;        // b' 0..63
    const int b0 = blockIdx.x << 6;

    {   // stage: coalesced global read of 64*34 ints, convert digit->tok embedding
        const float A = pA[0], th0 = pStart[0], dth = pStride[0];
        for (int e = threadIdx.y*64 + lane; e < 64*T34; e += 448) {
            int d = idx[b0*T34 + e];
            unsigned bp = (unsigned)e / 34u;
            int s = e - (int)(bp*34u);
            float ang = th0 + (float)d * dth;
            float ux = A * __cosf(ang);
            float uy = A * __sinf(ang);
            unsigned hx = (__float_as_uint(ux) + 0x8000u) >> 16;          // bf16 low half
            unsigned hy = (__float_as_uint(uy) + 0x8000u) & 0xffff0000u;  // bf16 high half
            su[bp*35u + (unsigned)s] = hy | hx;
        }
    }
    __syncthreads();

    int t = blockIdx.y*7 + threadIdx.y;
    if (t >= T34) return;                         // only wave (by=4,ty=6) idles
    const int tu = __builtin_amdgcn_readfirstlane(t);   // wave-uniform -> SGPR
    const float* __restrict__ Pr = ws + PW_OFF + tu*T34;
    const unsigned* __restrict__ srow = su + lane*35;

    // m2 = sum_{s<=t} P'[t,s] * tok_table[idx[b,s]]   (the whole attention)
    float m2x = 0.f, m2y = 0.f;
    for (int s = 0; s <= tu; ++s) {
        unsigned pk = srow[s];
        float P = Pr[s];                          // uniform addr -> s_load
        m2x = fmaf(P, __uint_as_float(pk << 16), m2x);
        m2y = fmaf(P, __uint_as_float(pk & 0xffff0000u), m2y);
    }

    // ---- epilogue: residual + rmsnorm + exact-gelu MLP + rmsnorm + head ----
    float g = m2x*ws[HA_OFF] + m2y*ws[HA_OFF+1];  // out5 @ out_proj_A
    unsigned pkt = srow[tu];
    float x0 = __uint_as_float(pkt << 16)         + g*opB[0];
    float x1 = __uint_as_float(pkt & 0xffff0000u) + g*opB[1];
    float x2 = ws[POS_OFF + 4*tu + 0] + g*opB[2];
    float x3 = ws[POS_OFF + 4*tu + 1] + g*opB[3];
    float x4 = ws[POS_OFF + 4*tu + 2] + g*opB[4];
    float w0 = wn[0], w1 = wn[1], w2 = wn[2], w3 = wn[3], w4 = wn[4];

    float inv1 = rsqrtf((x0*x0 + x1*x1 + x2*x2 + x3*x3 + x4*x4)*0.2f + 1e-5f);
    float h0 = x0*inv1*w0, h1 = x1*inv1*w1, h2 = x2*inv1*w2, h3 = x3*inv1*w3, h4 = x4*inv1*w4;
    float z0 = h0*fc1[0] + h1*fc1[1] + h2*fc1[2] + h3*fc1[3] + h4*fc1[4];
    float z1 = h0*fc1[5] + h1*fc1[6] + h2*fc1[7] + h3*fc1[8] + h4*fc1[9];
    float g0 = 0.5f*z0*(1.f + erff(z0*0.70710678118654752440f));
    float g1 = 0.5f*z1*(1.f + erff(z1*0.70710678118654752440f));
    x0 += g0*H[0] + g1*H[5];
    x1 += g0*H[1] + g1*H[6];
    x2 += g0*H[2] + g1*H[7];
    x3 += g0*H[3] + g1*H[8];
    x4 += g0*H[4] + g1*H[9];
    float inv2 = rsqrtf((x0*x0 + x1*x1 + x2*x2 + x3*x3 + x4*x4)*0.2f + 1e-5f);
    h0 = x0*inv2*w0; h1 = x1*inv2*w1; h2 = x2*inv2*w2; h3 = x3*inv2*w3; h4 = x4*inv2*w4;
    float p0 = h0*H[0] + h1*H[1] + h2*H[2] + h3*H[3] + h4*H[4];
    float p1 = h0*H[5] + h1*H[6] + h2*H[7] + h3*H[8] + h4*H[9];

    const float* tk = ws + TOK_OFF;
    float2* o = (float2*)(out + ((size_t)(b0 + lane)*T34 + (size_t)t)*10u);
    float2 r;
    r.x = p0*tk[0]  + p1*tk[1];  r.y = p0*tk[2]  + p1*tk[3];  o[0] = r;
    r.x = p0*tk[4]  + p1*tk[5];  r.y = p0*tk[6]  + p1*tk[7];  o[1] = r;
    r.x = p0*tk[8]  + p1*tk[9];  r.y = p0*tk[10] + p1*tk[11]; o[2] = r;
    r.x = p0*tk[12] + p1*tk[13]; r.y = p0*tk[14] + p1*tk[15]; o[3] = r;
    r.x = p0*tk[16] + p1*tk[17]; r.y = p0*tk[18] + p1*tk[19]; o[4] = r;
}

extern "C" void kernel_launch(void* const* d_in, const int* in_sizes, int n_in,
                              void* d_out, int out_size, void* d_ws, size_t ws_size,
                              hipStream_t stream)
{
    const int*   idx  = (const int*)  d_in[0];
    const float* pA   = (const float*)d_in[1];   // tok_arc_A
    const float* pSt  = (const float*)d_in[2];   // tok_arc_start
    const float* pSd  = (const float*)d_in[3];   // tok_arc_stride
    const float* zhi  = (const float*)d_in[4];   // z_hi_pos (3)
    const float* spe  = (const float*)d_in[5];   // special_pos_equals (3)
    const float* qw   = (const float*)d_in[6];   // q_proj_w (4x3)
    const float* qph  = (const float*)d_in[7];   // q_phase_angle (1)
    const float* opA  = (const float*)d_in[8];   // out_proj_A (5x1)
    const float* opB  = (const float*)d_in[9];   // out_proj_B (1x5)
    const float* wn   = (const float*)d_in[10];  // norm_weight (5)
    const float* fc1  = (const float*)d_in[11];  // fc1_w (2x5)
    const float* H    = (const float*)d_in[12];  // head_proj_w (2x5)
    float* ws  = (float*)d_ws;
    float* out = (float*)d_out;

    hipLaunchKernelGGL(prep_kernel, dim3(34), dim3(64), 0, stream,
                       pA, pSt, pSd, zhi, spe, qw, qph, opA, wn, H, ws);
    hipLaunchKernelGGL(micro_kernel, dim3(1024, 5), dim3(64, 7), 0, stream,
                       idx, pA, pSt, pSd, opB, wn, fc1, H, ws, out);
}

// Round 2
// 141.681 us; speedup vs baseline: 1.1425x; 1.1425x over previous
//
#include <hip/hip_runtime.h>
#include <math.h>

#define T34 34

// ws float offsets (P' padded to 35 rows; pos padded to 35 entries)
#define PW_OFF  0       // P'[35][34]  (row stride 34; row 34 = zeros)
#define TOK_OFF 1190    // tok_table[10][2]
#define POS_OFF 1216    // pos[35][4]  (raw pre-norm positional vectors; entry 34 = zeros)
#define HA_OFF  1356    // hA[2]

// ---------------------------------------------------------------------------
// Kernel A: build the batch-independent tables.
// Attention scores depend only on t because |tok[d]|^2 == A^2 for every digit,
// so rms(x) is digit-independent -> q,k are functions of t only.
// ---------------------------------------------------------------------------
__global__ __launch_bounds__(64) void prep_kernel(
    const float* __restrict__ pA, const float* __restrict__ pStart,
    const float* __restrict__ pStride, const float* __restrict__ zhi,
    const float* __restrict__ spe, const float* __restrict__ qw,
    const float* __restrict__ qph, const float* __restrict__ opA,
    const float* __restrict__ wn, const float* __restrict__ H,
    float* __restrict__ ws)
{
    __shared__ float sK[T34][4];   // k[t] = K0[t]/rho[t]
    __shared__ float sInv[T34];    // 1/rho[t]
    const int t = blockIdx.x;      // 0..33 : this block owns attention row t
    const int s = threadIdx.x;     // 0..63
    const float A = pA[0];

    if (s < T34) {
        // pos table per _SRC/_IDX/_OFFS: t<10 digit(t); 10 zeros; 11..20 digit(t-11);
        // 21 special_pos_equals; 22..31 digit(t-22); 32 z_hi_pos; 33 zeros.
        float p0 = 0.f, p1 = 0.f, p2 = 0.f;
        if (s == 21)      { p0 = spe[0]; p1 = spe[1]; p2 = spe[2]; }
        else if (s == 32) { p0 = zhi[0]; p1 = zhi[1]; p2 = zhi[2]; }
        else if (s != 10 && s != 33) {
            int i = (s < 10) ? s : (s < 21 ? s - 11 : s - 22);
            float a = 0.62831853071795864769f * (float)i;   // 2*pi*i/10
            p0 = 3.5f * cosf(a); p1 = 3.5f * sinf(a); p2 = 0.15f * (float)i;
        }
        float inv = rsqrtf((A*A + p0*p0 + p1*p1 + p2*p2) * 0.2f + 1e-5f);
        float c0 = p0 * wn[2], c1 = p1 * wn[3], c2 = p2 * wn[4];
        #pragma unroll
        for (int j = 0; j < 4; ++j)
            sK[s][j] = (c0*qw[j*3+0] + c1*qw[j*3+1] + c2*qw[j*3+2]) * inv;
        sInv[s] = inv;
        if (s == t) {
            ws[POS_OFF + 4*t + 0] = p0;
            ws[POS_OFF + 4*t + 1] = p1;
            ws[POS_OFF + 4*t + 2] = p2;
            ws[POS_OFF + 4*t + 3] = 0.f;
        }
    }
    __syncthreads();

    // rotate q for row t; k stays unrotated (k = q pre-rotation in the ref)
    float cc = cosf(qph[0]), sn = sinf(qph[0]);
    float k0 = sK[t][0], k1 = sK[t][1], k2 = sK[t][2], k3 = sK[t][3];
    float q0 = k0*cc - k1*sn, q1 = k0*sn + k1*cc;
    float q2 = k2*cc - k3*sn, q3 = k2*sn + k3*cc;

    // causal softmax row t (scores bounded ~|q||k|/2 < ~25 -> max-free exp safe)
    float e = 0.f;
    if (s <= t && s < T34) {
        float d = 0.5f*(q0*sK[s][0] + q1*sK[s][1] + q2*sK[s][2] + q3*sK[s][3]);
        e = expf(d);
    }
    float Z = e;
    #pragma unroll
    for (int off = 1; off < 64; off <<= 1) Z += __shfl_xor(Z, off);
    if (s < T34) ws[PW_OFF + t*T34 + s] = (s <= t) ? (e / Z) * sInv[s] : 0.f;

    if (t == 0) {
        if (s < T34) ws[PW_OFF + 34*T34 + s] = 0.f;   // zero pad row t=34
        if (s < 10) {
            float ang = pStart[0] + (float)s * pStride[0];
            ws[TOK_OFF + 2*s + 0] = A * cosf(ang);
            ws[TOK_OFF + 2*s + 1] = A * sinf(ang);
        } else if (s == 10) {
            // hA[j] = w[j] * sum_h H[j][h]*out_proj_A[h]  (collapses out@A@B to g*B)
            float a0 = 0.f, a1 = 0.f;
            #pragma unroll
            for (int h = 0; h < 5; ++h) { a0 += H[h]*opA[h]; a1 += H[5+h]*opA[h]; }
            ws[HA_OFF + 0] = a0 * wn[0];
            ws[HA_OFF + 1] = a1 * wn[1];
        } else if (s == 11) {
            ws[POS_OFF + 4*34 + 0] = 0.f;             // zero pad pos entry t=34
            ws[POS_OFF + 4*34 + 1] = 0.f;
            ws[POS_OFF + 4*34 + 2] = 0.f;
            ws[POS_OFF + 4*34 + 3] = 0.f;
        }
    }
}

// ---------------------------------------------------------------------------
// Kernel B: one block = 64 batches x ALL 34 t's (7 waves; wave ty owns
// t = ty+7j, j=0..4, with P' row 34 = 0 padding). Phase 1 stages idx once
// (int4 coalesced) as bf16-packed token embeddings; phase 2 runs the
// attention s-loop with 5 accumulator pairs (1 ds_read + 5 s_load + 10 fma
// per s) + scalar epilogue -> (p0,p1) to LDS; phase 3 expands via the 10x2
// head table and writes the block's CONTIGUOUS 87 KB output span as
// perfectly coalesced float2 streams.
// ---------------------------------------------------------------------------
__global__ __launch_bounds__(448) void micro_kernel(
    const int*  __restrict__ idx,
    const float* __restrict__ pA, const float* __restrict__ pStart,
    const float* __restrict__ pStride,
    const float* __restrict__ opB, const float* __restrict__ wn,
    const float* __restrict__ fc1, const float* __restrict__ H,
    const float* __restrict__ ws,
    float* __restrict__ out)
{
    __shared__ unsigned su[64*35];   // [b'][s] packed bf16x2 tok emb, stride 35
    __shared__ float    pr[64*35*2]; // [b'][t] (p0,p1), stride 35 pairs
    __shared__ float    stk[20];     // tok_table copy
    const int lane = threadIdx.x;    // b' 0..63
    const int ty   = threadIdx.y;    // 0..6
    const int tid  = ty*64 + lane;
    const int b0   = blockIdx.x << 6;

    // ---- phase 1: stage 64x34 idx (int4 coalesced) -> packed bf16 embeddings
    {
        const float A = pA[0], th0 = pStart[0], dth = pStride[0];
        if (tid < 20) stk[tid] = ws[TOK_OFF + tid];
        const int4* src4 = (const int4*)(idx + (size_t)b0*T34);
        for (int e4 = tid; e4 < (64*T34)/4; e4 += 448) {
            int4 d4 = src4[e4];
            int e = e4 << 2;
            #pragma unroll
            for (int k = 0; k < 4; ++k) {
                int d = (k==0) ? d4.x : (k==1) ? d4.y : (k==2) ? d4.z : d4.w;
                int ee = e + k;
                unsigned bp = (unsigned)ee / 34u;
                int s = ee - (int)(bp*34u);
                float ang = th0 + (float)d*dth;
                float ux = A*__cosf(ang), uy = A*__sinf(ang);
                unsigned hx = (__float_as_uint(ux) + 0x8000u) >> 16;
                unsigned hy = (__float_as_uint(uy) + 0x8000u) & 0xffff0000u;
                su[bp*35u + (unsigned)s] = hy | hx;
            }
        }
    }
    __syncthreads();

    // ---- phase 2: attention + epilogue for t = tyu + 7j, j=0..4
    {
        const int tyu = __builtin_amdgcn_readfirstlane(ty);  // wave-uniform
        const unsigned* __restrict__ srow = su + lane*35;
        const float* __restrict__ Pb = ws + PW_OFF + tyu*T34; // + j*238 + s

        float mx[5] = {0,0,0,0,0}, my[5] = {0,0,0,0,0};
        #pragma unroll
        for (int s = 0; s < T34; ++s) {
            unsigned pk = srow[s];
            float ux = __uint_as_float(pk << 16);
            float uy = __uint_as_float(pk & 0xffff0000u);
            #pragma unroll
            for (int j = 0; j < 5; ++j) {
                float P = Pb[j*7*T34 + s];     // uniform -> s_load imm offset
                mx[j] = fmaf(P, ux, mx[j]);
                my[j] = fmaf(P, uy, my[j]);
            }
        }

        const float hA0 = ws[HA_OFF], hA1 = ws[HA_OFF+1];
        const float w0=wn[0], w1=wn[1], w2=wn[2], w3=wn[3], w4=wn[4];
        const float ob0=opB[0], ob1=opB[1], ob2=opB[2], ob3=opB[3], ob4=opB[4];

        #pragma unroll
        for (int j = 0; j < 5; ++j) {
            const int t = tyu + 7*j;           // uniform; t=34 -> pad slots
            float g = mx[j]*hA0 + my[j]*hA1;   // out5 @ out_proj_A (collapsed)
            unsigned pkt = srow[t];
            float x0 = __uint_as_float(pkt << 16)         + g*ob0;
            float x1 = __uint_as_float(pkt & 0xffff0000u) + g*ob1;
            float x2 = ws[POS_OFF + 4*t + 0] + g*ob2;
            float x3 = ws[POS_OFF + 4*t + 1] + g*ob3;
            float x4 = ws[POS_OFF + 4*t + 2] + g*ob4;

            float inv1 = rsqrtf((x0*x0+x1*x1+x2*x2+x3*x3+x4*x4)*0.2f + 1e-5f);
            float h0=x0*inv1*w0, h1=x1*inv1*w1, h2=x2*inv1*w2, h3=x3*inv1*w3, h4=x4*inv1*w4;
            float z0 = h0*fc1[0]+h1*fc1[1]+h2*fc1[2]+h3*fc1[3]+h4*fc1[4];
            float z1 = h0*fc1[5]+h1*fc1[6]+h2*fc1[7]+h3*fc1[8]+h4*fc1[9];
            float g0 = 0.5f*z0*(1.f + erff(z0*0.70710678118654752440f));
            float g1 = 0.5f*z1*(1.f + erff(z1*0.70710678118654752440f));
            x0 += g0*H[0] + g1*H[5];
            x1 += g0*H[1] + g1*H[6];
            x2 += g0*H[2] + g1*H[7];
            x3 += g0*H[3] + g1*H[8];
            x4 += g0*H[4] + g1*H[9];
            float inv2 = rsqrtf((x0*x0+x1*x1+x2*x2+x3*x3+x4*x4)*0.2f + 1e-5f);
            h0=x0*inv2*w0; h1=x1*inv2*w1; h2=x2*inv2*w2; h3=x3*inv2*w3; h4=x4*inv2*w4;
            float p0 = h0*H[0]+h1*H[1]+h2*H[2]+h3*H[3]+h4*H[4];
            float p1 = h0*H[5]+h1*H[6]+h2*H[7]+h3*H[8]+h4*H[9];
            pr[(lane*35 + t)*2 + 0] = p0;      // t=34 lands in pad, never read
            pr[(lane*35 + t)*2 + 1] = p1;
        }
    }
    __syncthreads();

    // ---- phase 3: coalesced write of the block's contiguous 64*340-float span
    {
        float2* __restrict__ o = (float2*)out + (size_t)b0*170;
        for (int e = tid; e < 64*170; e += 448) {
            int bp = e / 170;
            int r  = e - 170*bp;
            int t  = r / 5;
            int j2 = r - 5*t;
            float p0 = pr[(bp*35 + t)*2 + 0];
            float p1 = pr[(bp*35 + t)*2 + 1];
            float2 v;
            v.x = p0*stk[4*j2+0] + p1*stk[4*j2+1];
            v.y = p0*stk[4*j2+2] + p1*stk[4*j2+3];
            o[e] = v;
        }
    }
}

extern "C" void kernel_launch(void* const* d_in, const int* in_sizes, int n_in,
                              void* d_out, int out_size, void* d_ws, size_t ws_size,
                              hipStream_t stream)
{
    const int*   idx  = (const int*)  d_in[0];
    const float* pA   = (const float*)d_in[1];   // tok_arc_A
    const float* pSt  = (const float*)d_in[2];   // tok_arc_start
    const float* pSd  = (const float*)d_in[3];   // tok_arc_stride
    const float* zhi  = (const float*)d_in[4];   // z_hi_pos (3)
    const float* spe  = (const float*)d_in[5];   // special_pos_equals (3)
    const float* qw   = (const float*)d_in[6];   // q_proj_w (4x3)
    const float* qph  = (const float*)d_in[7];   // q_phase_angle (1)
    const float* opA  = (const float*)d_in[8];   // out_proj_A (5x1)
    const float* opB  = (const float*)d_in[9];   // out_proj_B (1x5)
    const float* wn   = (const float*)d_in[10];  // norm_weight (5)
    const float* fc1  = (const float*)d_in[11];  // fc1_w (2x5)
    const float* H    = (const float*)d_in[12];  // head_proj_w (2x5)
    float* ws  = (float*)d_ws;
    float* out = (float*)d_out;

    hipLaunchKernelGGL(prep_kernel, dim3(34), dim3(64), 0, stream,
                       pA, pSt, pSd, zhi, spe, qw, qph, opA, wn, H, ws);
    hipLaunchKernelGGL(micro_kernel, dim3(1024), dim3(64, 7), 0, stream,
                       idx, pA, pSt, pSd, opB, wn, fc1, H, ws, out);
}

// Round 3
// 140.194 us; speedup vs baseline: 1.1546x; 1.0106x over previous
//
#include <hip/hip_runtime.h>
#include <math.h>

#define T34 34

// ws float offsets (P' stride 36, rows 0..34; row 34 and cols 34,35 are zero)
#define PW_OFF  0       // P'[35][36]
#define TOK_OFF 1260    // tok_table[10][2]
#define POS_OFF 1280    // pos[35][4] (raw pre-norm positional vectors; entry 34 = zeros)
#define HA_OFF  1420    // hA[2]

// ---------------------------------------------------------------------------
// Kernel A: build the batch-independent tables.
// Attention scores depend only on t because |tok[d]|^2 == A^2 for every digit,
// so rms(x) is digit-independent -> q,k are functions of t only.
// ---------------------------------------------------------------------------
__global__ __launch_bounds__(64) void prep_kernel(
    const float* __restrict__ pA, const float* __restrict__ pStart,
    const float* __restrict__ pStride, const float* __restrict__ zhi,
    const float* __restrict__ spe, const float* __restrict__ qw,
    const float* __restrict__ qph, const float* __restrict__ opA,
    const float* __restrict__ wn, const float* __restrict__ H,
    float* __restrict__ ws)
{
    __shared__ float sK[T34][4];   // k[t] = K0[t]/rho[t]
    __shared__ float sInv[T34];    // 1/rho[t]
    const int t = blockIdx.x;      // 0..33 : this block owns attention row t
    const int s = threadIdx.x;     // 0..63
    const float A = pA[0];

    if (s < T34) {
        // pos table per _SRC/_IDX/_OFFS: t<10 digit(t); 10 zeros; 11..20 digit(t-11);
        // 21 special_pos_equals; 22..31 digit(t-22); 32 z_hi_pos; 33 zeros.
        float p0 = 0.f, p1 = 0.f, p2 = 0.f;
        if (s == 21)      { p0 = spe[0]; p1 = spe[1]; p2 = spe[2]; }
        else if (s == 32) { p0 = zhi[0]; p1 = zhi[1]; p2 = zhi[2]; }
        else if (s != 10 && s != 33) {
            int i = (s < 10) ? s : (s < 21 ? s - 11 : s - 22);
            float a = 0.62831853071795864769f * (float)i;   // 2*pi*i/10
            p0 = 3.5f * cosf(a); p1 = 3.5f * sinf(a); p2 = 0.15f * (float)i;
        }
        float inv = rsqrtf((A*A + p0*p0 + p1*p1 + p2*p2) * 0.2f + 1e-5f);
        float c0 = p0 * wn[2], c1 = p1 * wn[3], c2 = p2 * wn[4];
        #pragma unroll
        for (int j = 0; j < 4; ++j)
            sK[s][j] = (c0*qw[j*3+0] + c1*qw[j*3+1] + c2*qw[j*3+2]) * inv;
        sInv[s] = inv;
        if (s == t) {
            ws[POS_OFF + 4*t + 0] = p0;
            ws[POS_OFF + 4*t + 1] = p1;
            ws[POS_OFF + 4*t + 2] = p2;
            ws[POS_OFF + 4*t + 3] = 0.f;
        }
    }
    __syncthreads();

    // rotate q for row t; k stays unrotated (k = q pre-rotation in the ref)
    float cc = cosf(qph[0]), sn = sinf(qph[0]);
    float k0 = sK[t][0], k1 = sK[t][1], k2 = sK[t][2], k3 = sK[t][3];
    float q0 = k0*cc - k1*sn, q1 = k0*sn + k1*cc;
    float q2 = k2*cc - k3*sn, q3 = k2*sn + k3*cc;

    // causal softmax row t (scores bounded ~|q||k|/2 < ~25 -> max-free exp safe)
    float e = 0.f;
    if (s <= t && s < T34) {
        float d = 0.5f*(q0*sK[s][0] + q1*sK[s][1] + q2*sK[s][2] + q3*sK[s][3]);
        e = expf(d);
    }
    float Z = e;
    #pragma unroll
    for (int off = 1; off < 64; off <<= 1) Z += __shfl_xor(Z, off);
    if (s < 36) ws[PW_OFF + t*36 + s] = (s <= t && s < T34) ? (e / Z) * sInv[s] : 0.f;

    if (t == 0) {
        if (s < 36) ws[PW_OFF + 34*36 + s] = 0.f;     // zero pad row t=34
        if (s < 10) {
            float ang = pStart[0] + (float)s * pStride[0];
            ws[TOK_OFF + 2*s + 0] = A * cosf(ang);
            ws[TOK_OFF + 2*s + 1] = A * sinf(ang);
        } else if (s == 10) {
            // hA[j] = w[j] * sum_h H[j][h]*out_proj_A[h]  (collapses out@A@B to g*B)
            float a0 = 0.f, a1 = 0.f;
            #pragma unroll
            for (int h = 0; h < 5; ++h) { a0 += H[h]*opA[h]; a1 += H[5+h]*opA[h]; }
            ws[HA_OFF + 0] = a0 * wn[0];
            ws[HA_OFF + 1] = a1 * wn[1];
        } else if (s == 11) {
            ws[POS_OFF + 4*34 + 0] = 0.f;             // zero pad pos entry t=34
            ws[POS_OFF + 4*34 + 1] = 0.f;
            ws[POS_OFF + 4*34 + 2] = 0.f;
            ws[POS_OFF + 4*34 + 3] = 0.f;
        }
    }
}

// ---------------------------------------------------------------------------
// Kernel B: one block = 64 batches x ALL 34 t's (7 waves; wave ty owns
// t = ty+7j, j=0..4, with P' row 34 = 0 padding).
//  phase 0: 10-entry packed-bf16 token LUT (kills per-element sincos)
//  phase 1: idx staged once (int4 coalesced) -> su via LDS LUT gather
//  phase 2: attention s-loop as 9x ds_read_b128 (stride 36, 16B aligned) with
//           5 accumulator pairs + scalar epilogue -> (p0,p1) to LDS
//  phase 3: float4 expansion of the block's CONTIGUOUS output span
// ---------------------------------------------------------------------------
__global__ __launch_bounds__(448) void micro_kernel(
    const int*  __restrict__ idx,
    const float* __restrict__ pA, const float* __restrict__ pStart,
    const float* __restrict__ pStride,
    const float* __restrict__ opB, const float* __restrict__ wn,
    const float* __restrict__ fc1, const float* __restrict__ H,
    const float* __restrict__ ws,
    float* __restrict__ out)
{
    __shared__ unsigned su[64*36];   // [b'][s] packed bf16x2 tok emb, stride 36 (16B aligned)
    __shared__ float    pr[64*35*2]; // [b'][t] (p0,p1), stride 35 pairs
    __shared__ float    stk[20];     // tok_table copy (f32)
    __shared__ unsigned lut[10];     // packed bf16x2 tok emb per digit
    const int lane = threadIdx.x;    // b' 0..63
    const int ty   = threadIdx.y;    // 0..6
    const int tid  = ty*64 + lane;
    const int b0   = blockIdx.x << 6;

    // ---- phase 0: tiny tables
    if (tid < 20) stk[tid] = ws[TOK_OFF + tid];
    if (tid >= 64 && tid < 74) {                 // wave 1 builds the digit LUT
        int d = tid - 64;
        float ang = pStart[0] + (float)d * pStride[0];
        float ux = pA[0]*__cosf(ang), uy = pA[0]*__sinf(ang);
        unsigned hx = (__float_as_uint(ux) + 0x8000u) >> 16;
        unsigned hy = (__float_as_uint(uy) + 0x8000u) & 0xffff0000u;
        lut[d] = hy | hx;
    }
    if (tid < 128) su[(tid >> 1)*36 + 34 + (tid & 1)] = 0u;   // zero s=34,35 pad
    __syncthreads();

    // ---- phase 1: stage 64x34 idx (int4 coalesced) -> LUT gather into su
    {
        const int4* src4 = (const int4*)(idx + (size_t)b0*T34);
        for (int e4 = tid; e4 < 544; e4 += 448) {            // 64*34/4
            int4 d4 = src4[e4];
            int e = e4 << 2;
            #pragma unroll
            for (int k = 0; k < 4; ++k) {
                int d = (k==0) ? d4.x : (k==1) ? d4.y : (k==2) ? d4.z : d4.w;
                int ee = e + k;
                unsigned bp = (unsigned)ee / 34u;
                int s = ee - (int)(bp*34u);
                su[bp*36u + (unsigned)s] = lut[d];           // <=10 distinct addrs: multicast
            }
        }
    }
    __syncthreads();

    // ---- phase 2: attention + epilogue for t = tyu + 7j, j=0..4
    {
        const int tyu = __builtin_amdgcn_readfirstlane(ty);  // wave-uniform
        const uint4* __restrict__ srow4 = (const uint4*)(su + lane*36);
        const float* __restrict__ Pb = ws + PW_OFF + tyu*36; // + j*252 + s (s_load imm)

        float mx[5] = {0,0,0,0,0}, my[5] = {0,0,0,0,0};
        #pragma unroll
        for (int s4 = 0; s4 < 9; ++s4) {
            uint4 pk4 = srow4[s4];                           // ds_read_b128
            #pragma unroll
            for (int k = 0; k < 4; ++k) {
                unsigned pk = (k==0) ? pk4.x : (k==1) ? pk4.y : (k==2) ? pk4.z : pk4.w;
                float ux = __uint_as_float(pk << 16);
                float uy = __uint_as_float(pk & 0xffff0000u);
                int s = s4*4 + k;
                #pragma unroll
                for (int j = 0; j < 5; ++j) {
                    float P = Pb[j*252 + s];                 // rows 34 / cols 34,35 are zero
                    mx[j] = fmaf(P, ux, mx[j]);
                    my[j] = fmaf(P, uy, my[j]);
                }
            }
        }

        const float hA0 = ws[HA_OFF], hA1 = ws[HA_OFF+1];
        const float w0=wn[0], w1=wn[1], w2=wn[2], w3=wn[3], w4=wn[4];
        const float ob0=opB[0], ob1=opB[1], ob2=opB[2], ob3=opB[3], ob4=opB[4];
        const unsigned* __restrict__ srow = su + lane*36;

        #pragma unroll
        for (int j = 0; j < 5; ++j) {
            const int t = tyu + 7*j;           // uniform; t=34 -> pad slots
            float g = mx[j]*hA0 + my[j]*hA1;   // out5 @ out_proj_A (collapsed)
            unsigned pkt = srow[t];
            float x0 = __uint_as_float(pkt << 16)         + g*ob0;
            float x1 = __uint_as_float(pkt & 0xffff0000u) + g*ob1;
            float x2 = ws[POS_OFF + 4*t + 0] + g*ob2;
            float x3 = ws[POS_OFF + 4*t + 1] + g*ob3;
            float x4 = ws[POS_OFF + 4*t + 2] + g*ob4;

            float inv1 = rsqrtf((x0*x0+x1*x1+x2*x2+x3*x3+x4*x4)*0.2f + 1e-5f);
            float h0=x0*inv1*w0, h1=x1*inv1*w1, h2=x2*inv1*w2, h3=x3*inv1*w3, h4=x4*inv1*w4;
            float z0 = h0*fc1[0]+h1*fc1[1]+h2*fc1[2]+h3*fc1[3]+h4*fc1[4];
            float z1 = h0*fc1[5]+h1*fc1[6]+h2*fc1[7]+h3*fc1[8]+h4*fc1[9];
            float g0 = 0.5f*z0*(1.f + erff(z0*0.70710678118654752440f));
            float g1 = 0.5f*z1*(1.f + erff(z1*0.70710678118654752440f));
            x0 += g0*H[0] + g1*H[5];
            x1 += g0*H[1] + g1*H[6];
            x2 += g0*H[2] + g1*H[7];
            x3 += g0*H[3] + g1*H[8];
            x4 += g0*H[4] + g1*H[9];
            float inv2 = rsqrtf((x0*x0+x1*x1+x2*x2+x3*x3+x4*x4)*0.2f + 1e-5f);
            h0=x0*inv2*w0; h1=x1*inv2*w1; h2=x2*inv2*w2; h3=x3*inv2*w3; h4=x4*inv2*w4;
            float p0 = h0*H[0]+h1*H[1]+h2*H[2]+h3*H[3]+h4*H[4];
            float p1 = h0*H[5]+h1*H[6]+h2*H[7]+h3*H[8]+h4*H[9];
            pr[(lane*35 + t)*2 + 0] = p0;      // t=34 lands in pad, never read
            pr[(lane*35 + t)*2 + 1] = p1;
        }
    }
    __syncthreads();

    // ---- phase 3: float4-coalesced write of the block's contiguous span
    {
        float4* __restrict__ o = (float4*)out + (size_t)b0*85;   // 340 floats/row = 85 float4
        for (int e4 = tid; e4 < 5440; e4 += 448) {               // 64*85
            int bp = e4 / 85;
            int r4 = e4 - 85*bp;
            float4 v;
            #pragma unroll
            for (int k = 0; k < 4; ++k) {
                int f = 4*r4 + k;
                int t = f / 10;
                int c = f - 10*t;
                float p0 = pr[(bp*35 + t)*2 + 0];
                float p1 = pr[(bp*35 + t)*2 + 1];
                ((float*)&v)[k] = p0*stk[2*c] + p1*stk[2*c+1];
            }
            o[e4] = v;
        }
    }
}

extern "C" void kernel_launch(void* const* d_in, const int* in_sizes, int n_in,
                              void* d_out, int out_size, void* d_ws, size_t ws_size,
                              hipStream_t stream)
{
    const int*   idx  = (const int*)  d_in[0];
    const float* pA   = (const float*)d_in[1];   // tok_arc_A
    const float* pSt  = (const float*)d_in[2];   // tok_arc_start
    const float* pSd  = (const float*)d_in[3];   // tok_arc_stride
    const float* zhi  = (const float*)d_in[4];   // z_hi_pos (3)
    const float* spe  = (const float*)d_in[5];   // special_pos_equals (3)
    const float* qw   = (const float*)d_in[6];   // q_proj_w (4x3)
    const float* qph  = (const float*)d_in[7];   // q_phase_angle (1)
    const float* opA  = (const float*)d_in[8];   // out_proj_A (5x1)
    const float* opB  = (const float*)d_in[9];   // out_proj_B (1x5)
    const float* wn   = (const float*)d_in[10];  // norm_weight (5)
    const float* fc1  = (const float*)d_in[11];  // fc1_w (2x5)
    const float* H    = (const float*)d_in[12];  // head_proj_w (2x5)
    float* ws  = (float*)d_ws;
    float* out = (float*)d_out;

    hipLaunchKernelGGL(prep_kernel, dim3(34), dim3(64), 0, stream,
                       pA, pSt, pSd, zhi, spe, qw, qph, opA, wn, H, ws);
    hipLaunchKernelGGL(micro_kernel, dim3(1024), dim3(64, 7), 0, stream,
                       idx, pA, pSt, pSd, opB, wn, fc1, H, ws, out);
}